// Round 3
// baseline (2999.914 us; speedup 1.0000x reference)
//
#include <hip/hip_runtime.h>
#include <math.h>

namespace {
constexpr int B = 8, T = 64, N = 2048, H = 64, F = 64, E = 32768, G = 192;
constexpr int BNH = B * N * H;   // 1048576
constexpr int NWELEM = N * G * H;  // 25165824 per weight tensor
}

typedef __attribute__((ext_vector_type(8))) short bfrag;   // 8 bf16 = 4 VGPRs
typedef __attribute__((ext_vector_type(4))) float ffrag;   // 4 fp32 acc

#define MFMA(a, b, c) __builtin_amdgcn_mfma_f32_16x16x32_bf16(a, b, c, 0, 0, 0)

__device__ __forceinline__ unsigned short f2bf(float f) {
  unsigned u = __float_as_uint(f);
  u += 0x7fffu + ((u >> 16) & 1u);   // RNE
  return (unsigned short)(u >> 16);
}

// ---------------- setup kernels ----------------

__global__ __launch_bounds__(256) void init_kernel(
    float* __restrict__ state, float* __restrict__ mA,
    const float* __restrict__ b_msg, float* __restrict__ loss_acc,
    float* __restrict__ scal, int* __restrict__ deg)
{
  int stride = gridDim.x * blockDim.x;
  for (int i = blockIdx.x * blockDim.x + threadIdx.x; i < BNH; i += stride) {
    state[i] = 0.f;
    mA[i] = b_msg[i & (H - 1)];       // step-0 message = 0 @ W_msg + b_msg
    if (i < N) { loss_acc[i] = 0.f; deg[i] = 0; }
    if (i < 16) scal[i] = 0.f;
  }
}

__global__ __launch_bounds__(256) void conv_kernel(
    const float* __restrict__ Wi, const float* __restrict__ Wh,
    const float* __restrict__ Wm, const float* __restrict__ Wg,
    unsigned short* __restrict__ Wib, unsigned short* __restrict__ Whb,
    unsigned short* __restrict__ Wmb, unsigned short* __restrict__ Wgb)
{
  int stride = gridDim.x * blockDim.x;
  for (int i = blockIdx.x * blockDim.x + threadIdx.x; i < NWELEM; i += stride) {
    Wib[i] = f2bf(Wi[i]);
    Whb[i] = f2bf(Wh[i]);
    if (i < 64 * 128) Wmb[i] = f2bf(Wm[i]);
    if (i < 64 * 64) Wgb[i] = f2bf(Wg[i]);
  }
}

__global__ __launch_bounds__(256) void hist_kernel(const int* __restrict__ ei, int* __restrict__ deg) {
  int e = blockIdx.x * 256 + threadIdx.x;
  if (e < E) atomicAdd(&deg[ei[E + e]], 1);   // row 1 = dst
}

__global__ __launch_bounds__(1024) void scan_kernel(const int* __restrict__ deg,
    int* __restrict__ row_ptr, int* __restrict__ cursor)
{
  __shared__ int s[N];
  int tid = threadIdx.x;
  s[tid] = deg[tid];
  s[tid + 1024] = deg[tid + 1024];
  __syncthreads();
  for (int off = 1; off < N; off <<= 1) {
    int v0 = (tid >= off) ? s[tid - off] : 0;
    int v1 = s[tid + 1024 - off];
    __syncthreads();
    s[tid] += v0;
    s[tid + 1024] += v1;
    __syncthreads();
  }
  row_ptr[tid + 1] = s[tid];
  row_ptr[tid + 1025] = s[tid + 1024];
  cursor[tid] = (tid == 0) ? 0 : s[tid - 1];
  cursor[tid + 1024] = s[tid + 1023];
  if (tid == 0) row_ptr[0] = 0;
}

__global__ __launch_bounds__(256) void fill_kernel(const int* __restrict__ ei,
    int* __restrict__ cursor, int* __restrict__ col_src)
{
  int e = blockIdx.x * 256 + threadIdx.x;
  if (e < E) {
    int d = ei[E + e];
    int slot = atomicAdd(&cursor[d], 1);
    col_src[slot] = ei[e];                  // row 0 = src
  }
}

__global__ __launch_bounds__(256) void mask_kernel(const int* __restrict__ mask, float* __restrict__ scal) {
  int stride = gridDim.x * blockDim.x;
  int v = 0;
  for (int i = blockIdx.x * blockDim.x + threadIdx.x; i < B * T * N; i += stride)
    v += (mask[i] != 0);
  for (int o = 1; o < 64; o <<= 1) v += __shfl_xor(v, o, 64);
  if ((threadIdx.x & 63) == 0) atomicAdd(&scal[0], (float)v);
}

// ---------------- per-step fused kernel ----------------
// one block (256 thr, 4 waves) per node. All matvecs via bf16 MFMA 16x16x32.
// ALL independent global loads (per-node GRU weights = the bulk of bytes, x,
// biases, targets) are issued at kernel entry into REGISTERS so their L3/HBM
// latency overlaps the edge-gather and mix phases. Register prefetch survives
// __syncthreads (no vmcnt drain needed for private dests).

__global__ __launch_bounds__(256) void step_kernel(
    const float* __restrict__ x, const float* __restrict__ targets,
    const int* __restrict__ mask, float* __restrict__ state,
    const unsigned short* __restrict__ W_ihb, const unsigned short* __restrict__ W_hhb,
    const unsigned short* __restrict__ W_mixb, const unsigned short* __restrict__ W_msgb,
    const float* __restrict__ b_ih, const float* __restrict__ b_hh,
    const float* __restrict__ b_mix, const float* __restrict__ b_msg,
    const float* __restrict__ W_read, const float* __restrict__ b_read,
    const int* __restrict__ row_ptr, const int* __restrict__ col_src,
    const float* __restrict__ m_cur, float* __restrict__ m_nxt,
    float* __restrict__ loss_acc, int t)
{
  __shared__ float sts[B * H];            // state, fp32, for pointwise
  __shared__ unsigned short aggA[B * 72]; // A-frag layouts, bf16, pad 72 (rows 16B-aligned)
  __shared__ unsigned short stsA[B * 72];
  __shared__ unsigned short m2A[B * 72];
  __shared__ unsigned short nsA[B * 72];
  __shared__ float gis[B * G];
  __shared__ float ghs[B * G];
  __shared__ float red[B];

  const int n = blockIdx.x;
  const int tid = threadIdx.x;
  const int w = tid >> 6, lane = tid & 63;
  const int mrow = lane & 15, quad = lane >> 4;

  // ======== ENTRY PREFETCH (independent of everything) ========
  // GRU weight B-fragments -> registers (48 VGPRs): the 96 MB/step stream.
  bfrag wI0[3], wI1[3], wH0[3], wH1[3];
  {
    const unsigned short* Wi = W_ihb + (size_t)n * G * H + mrow * H + quad * 8;
    const unsigned short* Wh = W_hhb + (size_t)n * G * H + mrow * H + quad * 8;
#pragma unroll
    for (int tt = 0; tt < 3; ++tt) {
      const int off = (w + tt * 4) * 16 * H;
      wI0[tt] = *(const bfrag*)(Wi + off);
      wI1[tt] = *(const bfrag*)(Wi + off + 32);
      wH0[tt] = *(const bfrag*)(Wh + off);
      wH1[tt] = *(const bfrag*)(Wh + off + 32);
    }
  }
  // x_t A-fragments (HBM, ~900cy latency) -> registers
  float xv0[8], xv1[8];
  if (mrow < 8) {
    const float* xp = x + (((size_t)mrow * T + t) * N + n) * F + quad * 8;
    *(float4*)&xv0[0] = *(const float4*)(xp);
    *(float4*)&xv0[4] = *(const float4*)(xp + 4);
    *(float4*)&xv1[0] = *(const float4*)(xp + 32);
    *(float4*)&xv1[4] = *(const float4*)(xp + 32 + 4);
  }
  // GRU biases for phase C (lane == h)
  const float bir = b_ih[n * G + lane], biz = b_ih[n * G + 64 + lane], bin_ = b_ih[n * G + 128 + lane];
  const float bhr = b_hh[n * G + lane], bhz = b_hh[n * G + 64 + lane], bhn = b_hh[n * G + 128 + lane];
  const float wrd = W_read[lane];
  // targets/mask for the two batches this wave reduces (lane 0 only uses them)
  float tg0 = 0.f, tg1 = 0.f; int mk0 = 0, mk1 = 0;
  if (lane == 0) {
    size_t i0 = ((size_t)(2 * w) * T + t) * N + n;
    size_t i1 = ((size_t)(2 * w + 1) * T + t) * N + n;
    tg0 = targets[i0]; tg1 = targets[i1];
    mk0 = mask[i0]; mk1 = mask[i1];
  }
  const int e0 = row_ptr[n], e1 = row_ptr[n + 1];

  // ---- Phase A: state load + edge gather (wave w handles batches 2w, 2w+1)
  {
    const int h = lane;
    const int b0 = 2 * w, b1 = 2 * w + 1;
    float s0 = state[((size_t)b0 * N + n) * H + h];
    float s1 = state[((size_t)b1 * N + n) * H + h];
    sts[b0 * H + h] = s0; sts[b1 * H + h] = s1;
    stsA[b0 * 72 + h] = f2bf(s0); stsA[b1 * 72 + h] = f2bf(s1);
    float a0 = 0.f, a1 = 0.f;
    const float* mb0 = m_cur + (size_t)b0 * N * H;
    const float* mb1 = m_cur + (size_t)b1 * N * H;
    for (int e = e0; e < e1; ++e) {
      int src = col_src[e] * H;
      a0 += mb0[src + h];
      a1 += mb1[src + h];
    }
    aggA[b0 * 72 + h] = f2bf(a0); aggA[b1 * 72 + h] = f2bf(a1);
  }
  __syncthreads();

  // ---- Phase B1: m2 = W_mix @ [agg; x] (+b_mix). Wave w -> m2 cols [16w,16w+16)
  // W_mix is block-uniform (16 KB total) -> L1/L2-hot, load on demand.
  {
    const int g0 = w * 16;
    bfrag za = (bfrag)0;
    bfrag a0 = (mrow < 8) ? *(const bfrag*)&aggA[mrow * 72 + quad * 8] : za;
    bfrag a1 = (mrow < 8) ? *(const bfrag*)&aggA[mrow * 72 + 32 + quad * 8] : za;
    bfrag a2 = za, a3 = za;
    if (mrow < 8) {
#pragma unroll
      for (int j = 0; j < 8; ++j) { a2[j] = (short)f2bf(xv0[j]); a3[j] = (short)f2bf(xv1[j]); }
    }
    const unsigned short* wm = W_mixb + (g0 + mrow) * 128 + quad * 8;
    ffrag acc = {0.f, 0.f, 0.f, 0.f};
    acc = MFMA(a0, *(const bfrag*)(wm), acc);
    acc = MFMA(a1, *(const bfrag*)(wm + 32), acc);
    acc = MFMA(a2, *(const bfrag*)(wm + 64), acc);
    acc = MFMA(a3, *(const bfrag*)(wm + 96), acc);
    if (quad < 2) {
      float bm = b_mix[g0 + mrow];
#pragma unroll
      for (int r = 0; r < 4; ++r)
        m2A[(quad * 4 + r) * 72 + g0 + mrow] = f2bf(acc[r] + bm);
    }
  }
  __syncthreads();

  // ---- Phase B2: gi = m2 @ W_ih^T, gh = state @ W_hh^T (prefetched B-frags)
  {
    bfrag za = (bfrag)0;
    bfrag am0 = (mrow < 8) ? *(const bfrag*)&m2A[mrow * 72 + quad * 8] : za;
    bfrag am1 = (mrow < 8) ? *(const bfrag*)&m2A[mrow * 72 + 32 + quad * 8] : za;
    bfrag as0 = (mrow < 8) ? *(const bfrag*)&stsA[mrow * 72 + quad * 8] : za;
    bfrag as1 = (mrow < 8) ? *(const bfrag*)&stsA[mrow * 72 + 32 + quad * 8] : za;
#pragma unroll
    for (int tt = 0; tt < 3; ++tt) {
      const int g0 = (w + tt * 4) * 16;
      ffrag ai = {0.f, 0.f, 0.f, 0.f};
      ffrag ah = {0.f, 0.f, 0.f, 0.f};
      ai = MFMA(am0, wI0[tt], ai);
      ai = MFMA(am1, wI1[tt], ai);
      ah = MFMA(as0, wH0[tt], ah);
      ah = MFMA(as1, wH1[tt], ah);
      if (quad < 2) {
#pragma unroll
        for (int r = 0; r < 4; ++r) {
          gis[(quad * 4 + r) * G + g0 + mrow] = ai[r];
          ghs[(quad * 4 + r) * G + g0 + mrow] = ah[r];
        }
      }
    }
  }
  __syncthreads();

  // ---- Phase C: GRU pointwise + readout + loss. Wave w -> batches 2w, 2w+1.
  {
    const int h = lane;
    const float br = b_read[0];
#pragma unroll
    for (int bb = 0; bb < 2; ++bb) {
      const int b = 2 * w + bb;
      float ir = gis[b * G + h] + bir;
      float iz = gis[b * G + 64 + h] + biz;
      float in_ = gis[b * G + 128 + h] + bin_;
      float hr = ghs[b * G + h] + bhr;
      float hz = ghs[b * G + 64 + h] + bhz;
      float hn = ghs[b * G + 128 + h] + bhn;
      float r = 1.f / (1.f + __expf(-(ir + hr)));
      float z = 1.f / (1.f + __expf(-(iz + hz)));
      float pre = in_ + r * hn;
      float a = __expf(-2.f * fabsf(pre));
      float nc = copysignf((1.f - a) / (1.f + a), pre);   // stable tanh
      float ns = (1.f - z) * nc + z * sts[b * H + h];
      state[((size_t)b * N + n) * H + h] = ns;
      nsA[b * 72 + h] = f2bf(ns);
      float v = ns * wrd;
#pragma unroll
      for (int o = 32; o >= 1; o >>= 1) v += __shfl_xor(v, o, 64);
      if (h == 0) {
        float tgt = bb ? tg1 : tg0;
        int mk = bb ? mk1 : mk0;
        float d = (v + br) - tgt;
        red[b] = mk ? 0.5f * d * d : 0.f;
      }
    }
  }
  __syncthreads();

  // ---- Phase D: m_next = W_msg @ ns + b_msg. Wave w -> cols [16w,16w+16)
  // W_msg block-uniform (8 KB) -> L1-hot.
  {
    const int g0 = w * 16;
    bfrag za = (bfrag)0;
    bfrag an0 = (mrow < 8) ? *(const bfrag*)&nsA[mrow * 72 + quad * 8] : za;
    bfrag an1 = (mrow < 8) ? *(const bfrag*)&nsA[mrow * 72 + 32 + quad * 8] : za;
    const unsigned short* wg = W_msgb + (g0 + mrow) * H + quad * 8;
    ffrag acc = {0.f, 0.f, 0.f, 0.f};
    acc = MFMA(an0, *(const bfrag*)(wg), acc);
    acc = MFMA(an1, *(const bfrag*)(wg + 32), acc);
    if (quad < 2) {
      float bm = b_msg[g0 + mrow];
#pragma unroll
      for (int r = 0; r < 4; ++r)
        m_nxt[((size_t)(quad * 4 + r) * N + n) * H + g0 + mrow] = acc[r] + bm;
    }
  }
  if (tid == 0) {
    float s = red[0] + red[1] + red[2] + red[3] + red[4] + red[5] + red[6] + red[7];
    loss_acc[n] += s;
  }
}

__global__ __launch_bounds__(256) void final_kernel(const float* __restrict__ loss_acc,
    const float* __restrict__ scal, float* __restrict__ out)
{
  __shared__ float sred[4];
  float v = 0.f;
  for (int i = threadIdx.x; i < N; i += 256) v += loss_acc[i];
  for (int o = 1; o < 64; o <<= 1) v += __shfl_xor(v, o, 64);
  if ((threadIdx.x & 63) == 0) sred[threadIdx.x >> 6] = v;
  __syncthreads();
  if (threadIdx.x == 0) out[0] = (sred[0] + sred[1] + sred[2] + sred[3]) / scal[0];
}

extern "C" void kernel_launch(void* const* d_in, const int* in_sizes, int n_in,
                              void* d_out, int out_size, void* d_ws, size_t ws_size,
                              hipStream_t stream)
{
  const float* x       = (const float*)d_in[0];
  const float* targets = (const float*)d_in[1];
  const int*   mask    = (const int*)d_in[2];
  const int*   ei      = (const int*)d_in[3];
  const float* W_msg   = (const float*)d_in[4];
  const float* b_msg   = (const float*)d_in[5];
  const float* W_mix   = (const float*)d_in[6];
  const float* b_mix   = (const float*)d_in[7];
  const float* W_ih    = (const float*)d_in[8];
  const float* W_hh    = (const float*)d_in[9];
  const float* b_ih    = (const float*)d_in[10];
  const float* b_hh    = (const float*)d_in[11];
  const float* W_read  = (const float*)d_in[12];
  const float* b_read  = (const float*)d_in[13];
  float* out = (float*)d_out;

  float* state    = (float*)d_ws;
  float* mA       = state + BNH;
  float* mB       = mA + BNH;
  float* loss_acc = mB + BNH;
  float* scal     = loss_acc + N;
  int* deg        = (int*)(scal + 16);
  int* row_ptr    = deg + N;
  int* cursor     = row_ptr + (N + 16);
  int* col_src    = cursor + N;
  unsigned short* W_ihb  = (unsigned short*)(col_src + E);   // 16B aligned
  unsigned short* W_hhb  = W_ihb + NWELEM;
  unsigned short* W_mixb = W_hhb + NWELEM;
  unsigned short* W_msgb = W_mixb + 64 * 128;
  // total ws use ~113 MB

  init_kernel<<<1024, 256, 0, stream>>>(state, mA, b_msg, loss_acc, scal, deg);
  conv_kernel<<<8192, 256, 0, stream>>>(W_ih, W_hh, W_mix, W_msg, W_ihb, W_hhb, W_mixb, W_msgb);
  hist_kernel<<<E / 256, 256, 0, stream>>>(ei, deg);
  scan_kernel<<<1, 1024, 0, stream>>>(deg, row_ptr, cursor);
  fill_kernel<<<E / 256, 256, 0, stream>>>(ei, cursor, col_src);
  mask_kernel<<<512, 256, 0, stream>>>(mask, scal);

  float* mcur = mA;
  float* mnxt = mB;
  for (int t = 0; t < T; ++t) {
    step_kernel<<<N, 256, 0, stream>>>(x, targets, mask, state,
                                       W_ihb, W_hhb, W_mixb, W_msgb,
                                       b_ih, b_hh, b_mix, b_msg, W_read, b_read,
                                       row_ptr, col_src, mcur, mnxt, loss_acc, t);
    float* tmp = mcur; mcur = mnxt; mnxt = tmp;
  }
  final_kernel<<<1, 256, 0, stream>>>(loss_acc, scal, out);
}